// Round 7
// baseline (448.567 us; speedup 1.0000x reference)
//
#include <hip/hip_runtime.h>
#include <math.h>

#define NB 32
#define NC 256
#define SH 56
#define SW 56
#define HW 3136      // 56*56
#define HW4 784      // float4 per image plane
#define PERB4 (NC * HW4)   // 200704 float4 per image
#define NCG 8              // producer channel-groups per image (32 ch each)
#define NPROD (NB * NCG)         // 256 producer blocks
#define NCONS_PER_B 14           // consumers per image (4 rows each)
#define NCONS (NB * NCONS_PER_B) // 448 consumer blocks

__device__ __forceinline__ float4 max4(float4 a, float4 b) {
    return make_float4(fmaxf(a.x,b.x), fmaxf(a.y,b.y), fmaxf(a.z,b.z), fmaxf(a.w,b.w));
}
__device__ __forceinline__ float4 add4(float4 a, float4 b) {
    return make_float4(a.x+b.x, a.y+b.y, a.z+b.z, a.w+b.w);
}

// Single dispatch, producer-consumer via per-image device-scope flags.
// Producers (bid<256): reduce 32-ch slice of image b -> pmax/psum, bump done[b].
// Consumers: spin until done[b]==8, combine+conv+sigmoid -> gate rows, multiply
// their 4-row strip of all 256 channels.
// Grid 704 blocks @ launch_bounds(256,4) => all co-resident (cap 1024): no
// dispatch-order deadlock possible (G16).
__global__ __launch_bounds__(256, 4) void k_pc(const float4* __restrict__ x,
                                               const float* __restrict__ cw,
                                               const float* __restrict__ gamma,
                                               const float* __restrict__ beta,
                                               const float* __restrict__ rmean,
                                               const float* __restrict__ rvar,
                                               float4* __restrict__ out,
                                               float4* __restrict__ pmax,
                                               float4* __restrict__ psum,
                                               int* __restrict__ done) {
    const int tid = threadIdx.x;
    const int bid = blockIdx.x;

    if (bid < NPROD) {
        // ---------------- producer: (b, cg) ----------------
        const int b  = bid >> 3;
        const int cg = bid & 7;
        const float4* base = x + (size_t)b * PERB4 + (size_t)cg * (32 * HW4);

        const float NEG = -__builtin_inff();
        float4 m[4], s[4];
        #pragma unroll
        for (int j = 0; j < 4; ++j) {
            m[j] = make_float4(NEG,NEG,NEG,NEG);
            s[j] = make_float4(0.f,0.f,0.f,0.f);
        }
        for (int c = 0; c < 32; ++c) {
            const float4* row = base + (size_t)c * HW4;
            #pragma unroll
            for (int j = 0; j < 4; ++j) {
                const int idx = j * 256 + tid;
                if (idx < HW4) {
                    const float4 v = row[idx];
                    m[j] = max4(m[j], v);
                    s[j] = add4(s[j], v);
                }
            }
        }
        float4* pm = pmax + (size_t)bid * HW4;
        float4* ps = psum + (size_t)bid * HW4;
        #pragma unroll
        for (int j = 0; j < 4; ++j) {
            const int idx = j * 256 + tid;
            if (idx < HW4) { pm[idx] = m[j]; ps[idx] = s[j]; }
        }
        __threadfence();              // device-scope: publish partials
        __syncthreads();
        if (tid == 0) atomicAdd(&done[b * 16], 1);
        return;
    }

    // ---------------- consumer: (b, rs) -> rows 4rs..4rs+3 ----------------
    __shared__ float sw[99];
    __shared__ __align__(16) float smx[10 * SW];
    __shared__ __align__(16) float sav[10 * SW];
    __shared__ __align__(16) float sgate[4 * SW];

    const int cid = bid - NPROD;
    const int b   = cid / NCONS_PER_B;
    const int rs  = cid - b * NCONS_PER_B;

    const float inv = gamma[0] * rsqrtf(rvar[0] + 1e-5f);
    if (tid < 98) sw[tid] = cw[tid] * inv;
    if (tid == 0) sw[98] = beta[0] - rmean[0] * inv;

    if (tid == 0) {
        while (__hip_atomic_load(&done[b * 16], __ATOMIC_ACQUIRE,
                                 __HIP_MEMORY_SCOPE_AGENT) < NCG) {
            __builtin_amdgcn_s_sleep(8);
        }
    }
    __syncthreads();

    // combine 8 partials over halo rows [4rs-3, 4rs+6] clamped
    const int r0  = 4 * rs - 3;
    const int rlo = r0 > 0 ? r0 : 0;
    const int rhi = (4 * rs + 6) < (SH - 1) ? (4 * rs + 6) : (SH - 1);
    const int n4  = (rhi - rlo + 1) * 14;       // <= 140 float4
    const int sh4 = (rlo - r0) * 14;
    if (tid < n4) {
        const size_t pb = (size_t)(b * NCG) * HW4 + rlo * 14 + tid;
        float4 mm = pmax[pb];
        float4 ss = psum[pb];
        #pragma unroll
        for (int cg = 1; cg < NCG; ++cg) {
            mm = max4(mm, pmax[pb + (size_t)cg * HW4]);
            ss = add4(ss, psum[pb + (size_t)cg * HW4]);
        }
        const float r = 1.0f / 256.0f;
        ss.x *= r; ss.y *= r; ss.z *= r; ss.w *= r;
        ((float4*)smx)[sh4 + tid] = mm;
        ((float4*)sav)[sh4 + tid] = ss;
    }
    __syncthreads();

    // conv + BN + sigmoid for 224 px (4 rows)
    if (tid < 224) {
        const int lr = tid / 56;                // 0..3
        const int w  = tid - lr * 56;
        const int hr = 4 * rs + lr;
        float acc = sw[98];
        #pragma unroll
        for (int kh = 0; kh < 7; ++kh) {
            const int hh = hr + kh - 3;
            if (hh < 0 || hh >= SH) continue;
            const int slot = lr + kh;           // hh - r0
            #pragma unroll
            for (int kw = 0; kw < 7; ++kw) {
                const int ww = w + kw - 3;
                if (ww < 0 || ww >= SW) continue;
                acc += smx[slot * SW + ww] * sw[kh * 7 + kw]
                     + sav[slot * SW + ww] * sw[49 + kh * 7 + kw];
            }
        }
        sgate[tid] = 1.0f / (1.0f + expf(-acc));
    }
    __syncthreads();

    // multiply strip: 256 ch x 56 float4 (rows 4rs..4rs+3)
    const float4* sg4 = (const float4*)sgate;
    const size_t strip = (size_t)b * PERB4 + (size_t)rs * 56;
    #pragma unroll 4
    for (int it = 0; it < 56; ++it) {
        const unsigned idx = (unsigned)it * 256u + (unsigned)tid;  // 0..14335
        const unsigned c = idx / 56u;
        const unsigned q = idx - c * 56u;
        const size_t off = strip + (size_t)c * HW4 + q;
        const float4 g  = sg4[q];
        const float4 xv = x[off];
        out[off] = make_float4(xv.x * g.x, xv.y * g.y, xv.z * g.z, xv.w * g.w);
    }
}

extern "C" void kernel_launch(void* const* d_in, const int* in_sizes, int n_in,
                              void* d_out, int out_size, void* d_ws, size_t ws_size,
                              hipStream_t stream) {
    const float4* x4   = (const float4*)d_in[0];
    const float* cw    = (const float*)d_in[1];
    const float* gamma = (const float*)d_in[2];
    const float* beta  = (const float*)d_in[3];
    const float* rmean = (const float*)d_in[4];
    const float* rvar  = (const float*)d_in[5];
    float4* out4 = (float4*)d_out;

    // ws: pmax [256*784 f4] | psum [256*784 f4] | done [32*16 int]
    float4* pmax = (float4*)d_ws;
    float4* psum = pmax + (size_t)NPROD * HW4;
    int*    done = (int*)(psum + (size_t)NPROD * HW4);

    hipMemsetAsync(done, 0, NB * 16 * sizeof(int), stream);

    k_pc<<<NPROD + NCONS, 256, 0, stream>>>(
        x4, cw, gamma, beta, rmean, rvar, out4, pmax, psum, done);
}

// Round 9
// 278.987 us; speedup vs baseline: 1.6078x; 1.6078x over previous
//
#include <hip/hip_runtime.h>
#include <math.h>

#define NB 32
#define NC 256
#define SH 56
#define SW 56
#define HW 3136      // 56*56
#define HW4 784      // float4 per image plane
#define PERB4 (NC * HW4)   // 200704 float4 per image
#define BPI 49             // reduce blocks per image (16 float4-positions each)

__device__ __forceinline__ float4 max4(float4 a, float4 b) {
    return make_float4(fmaxf(a.x,b.x), fmaxf(a.y,b.y), fmaxf(a.z,b.z), fmaxf(a.w,b.w));
}
__device__ __forceinline__ float4 add4(float4 a, float4 b) {
    return make_float4(a.x+b.x, a.y+b.y, a.z+b.z, a.w+b.w);
}

// ---------------------------------------------------------------------------
// Kernel 1: reduce + (last block per image) conv+BN+sigmoid.
// Grid 32*49=1568. Block (b,pc): 16 float4 positions x 16 cgroups(16ch).
// Thread (cg,pos) reduces 16 channels at one position; LDS 16-way combine;
// final mx/av written by threads 0..15. Then done[b] atomicAdd; the 49th
// arriver (old==48) computes the whole image's gate (no spinning).
// ---------------------------------------------------------------------------
__global__ __launch_bounds__(256) void k_reduce_conv(const float4* __restrict__ x,
                                                     const float* __restrict__ cw,
                                                     const float* __restrict__ gamma,
                                                     const float* __restrict__ beta,
                                                     const float* __restrict__ rmean,
                                                     const float* __restrict__ rvar,
                                                     float4* __restrict__ mx4,
                                                     float4* __restrict__ av4,
                                                     float* __restrict__ gate,
                                                     int* __restrict__ done) {
    __shared__ __align__(16) float shraw[6528];   // 25.5 KB union
    __shared__ int sflag;
    const int tid = threadIdx.x;
    const int b   = blockIdx.x / BPI;
    const int pc  = blockIdx.x - b * BPI;

    // ---- producer phase ----
    {
        float4* smax = (float4*)shraw;            // [16cg][16pos]
        float4* ssum = smax + 256;
        const int pos = tid & 15;
        const int cg  = tid >> 4;
        const int p4  = pc * 16 + pos;            // 0..783
        const float4* base = x + (size_t)b * PERB4 + (size_t)(cg * 16) * HW4 + p4;

        const float NEG = -__builtin_inff();
        float4 m = make_float4(NEG,NEG,NEG,NEG);
        float4 s = make_float4(0.f,0.f,0.f,0.f);
        #pragma unroll
        for (int c = 0; c < 16; ++c) {
            const float4 v = base[(size_t)c * HW4];
            m = max4(m, v); s = add4(s, v);
        }
        smax[cg * 16 + pos] = m;
        ssum[cg * 16 + pos] = s;
        __syncthreads();
        if (tid < 16) {
            float4 mm = smax[tid];
            float4 ss = ssum[tid];
            #pragma unroll
            for (int q = 1; q < 16; ++q) {
                mm = max4(mm, smax[q * 16 + tid]);
                ss = add4(ss, ssum[q * 16 + tid]);
            }
            const float r = 1.0f / 256.0f;
            ss.x *= r; ss.y *= r; ss.z *= r; ss.w *= r;
            mx4[(size_t)b * HW4 + pc * 16 + tid] = mm;
            av4[(size_t)b * HW4 + pc * 16 + tid] = ss;
        }
        __threadfence();                          // publish partials (release)
        __syncthreads();
        if (tid == 0) sflag = atomicAdd(&done[b], 1);
        __syncthreads();
        if (sflag != BPI - 1) return;             // uniform branch
    }

    // ---- last arriver for image b: conv + BN + sigmoid ----
    __builtin_amdgcn_fence(__ATOMIC_ACQUIRE, "agent");
    __syncthreads();
    {
        float* smx = shraw;                       // [3136]
        float* sav = shraw + HW;                  // [3136]
        float* sw  = shraw + 2 * HW;              // [99]
        const float inv = gamma[0] * rsqrtf(rvar[0] + 1e-5f);
        if (tid < 98) sw[tid] = cw[tid] * inv;
        if (tid == 0) sw[98] = beta[0] - rmean[0] * inv;
        // stage mx/av for whole image (784 float4 each)
        for (int i = tid; i < HW4; i += 256) {
            ((float4*)smx)[i] = mx4[(size_t)b * HW4 + i];
            ((float4*)sav)[i] = av4[(size_t)b * HW4 + i];
        }
        __syncthreads();

        for (int px = tid; px < HW; px += 256) {
            const int h = px / SW;
            const int w = px - h * SW;
            float acc = sw[98];
            #pragma unroll
            for (int kh = 0; kh < 7; ++kh) {
                const int hh = h + kh - 3;
                if (hh < 0 || hh >= SH) continue;
                #pragma unroll
                for (int kw = 0; kw < 7; ++kw) {
                    const int ww = w + kw - 3;
                    if (ww < 0 || ww >= SW) continue;
                    acc += smx[hh * SW + ww] * sw[kh * 7 + kw]
                         + sav[hh * SW + ww] * sw[49 + kh * 7 + kw];
                }
            }
            gate[(size_t)b * HW + px] = 1.0f / (1.0f + expf(-acc));
        }
    }
}

// ---------------------------------------------------------------------------
// Kernel 2: out = x * gate, linear slabs + LDS-staged gate[b].
// Grid 32*49=1568, block streams 4096 contiguous float4 within one image.
// ---------------------------------------------------------------------------
__global__ __launch_bounds__(256) void k_mul(const float4* __restrict__ x,
                                             const float4* __restrict__ gate4,
                                             float4* __restrict__ out) {
    __shared__ float4 sgate[HW4];                 // 12.5 KB
    const int tid  = threadIdx.x;
    const int b    = blockIdx.x / BPI;
    const int slab = blockIdx.x - b * BPI;

    for (int i = tid; i < HW4; i += 256)
        sgate[i] = gate4[(size_t)b * HW4 + i];
    __syncthreads();

    const unsigned lbase = (unsigned)slab * 4096u + (unsigned)tid;
    const size_t   gbase = (size_t)b * PERB4;
    #pragma unroll
    for (int i = 0; i < 16; ++i) {
        const unsigned local = lbase + (unsigned)i * 256u;   // 0..200703
        const unsigned p4    = local % (unsigned)HW4;
        const float4 g  = sgate[p4];
        const float4 xv = x[gbase + local];
        out[gbase + local] = make_float4(xv.x * g.x, xv.y * g.y, xv.z * g.z, xv.w * g.w);
    }
}

extern "C" void kernel_launch(void* const* d_in, const int* in_sizes, int n_in,
                              void* d_out, int out_size, void* d_ws, size_t ws_size,
                              hipStream_t stream) {
    const float4* x4   = (const float4*)d_in[0];
    const float* cw    = (const float*)d_in[1];
    const float* gamma = (const float*)d_in[2];
    const float* beta  = (const float*)d_in[3];
    const float* rmean = (const float*)d_in[4];
    const float* rvar  = (const float*)d_in[5];
    float4* out4 = (float4*)d_out;

    // ws: mx4 [25088 f4] | av4 [25088 f4] | gate [100352 f] | done [32 int]
    float4* mx4  = (float4*)d_ws;
    float4* av4  = mx4 + (size_t)NB * HW4;
    float*  gate = (float*)(av4 + (size_t)NB * HW4);
    int*    done = (int*)(gate + (size_t)NB * HW);

    (void)hipMemsetAsync(done, 0, NB * sizeof(int), stream);

    k_reduce_conv<<<NB * BPI, 256, 0, stream>>>(
        x4, cw, gamma, beta, rmean, rvar, mx4, av4, gate, done);

    k_mul<<<NB * BPI, 256, 0, stream>>>(
        x4, (const float4*)gate, out4);
}

// Round 10
// 68.584 us; speedup vs baseline: 6.5404x; 4.0678x over previous
//
#include <hip/hip_runtime.h>
#include <math.h>

#define NB 32
#define NC 256
#define SH 56
#define SW 56
#define HW 3136      // 56*56
#define HW4 784      // float4 per image plane
#define PERB4 (NC * HW4)   // 200704 float4 per image
#define SROWS 7            // output rows per block strip
#define STRIPS 8           // strips per image (56/7)

__device__ __forceinline__ float4 max4(float4 a, float4 b) {
    return make_float4(fmaxf(a.x,b.x), fmaxf(a.y,b.y), fmaxf(a.z,b.z), fmaxf(a.w,b.w));
}
__device__ __forceinline__ float4 add4(float4 a, float4 b) {
    return make_float4(a.x+b.x, a.y+b.y, a.z+b.z, a.w+b.w);
}

// ---------------------------------------------------------------------------
// Single kernel, zero cross-block communication (halo-redundant):
// Block (b, s) owns rows [7s, 7s+6]. Phase 1: channel max/mean over the
// halo rows [7s-3, 7s+9] (clamped; nh<=13 rows) -> LDS. Each active thread
// owns one float4 position of the halo slab and loops all 256 channels
// (contiguous nh*224B slab per channel; rows are contiguous in-plane).
// Phase 2: 7x7 conv + folded BN + sigmoid from LDS -> sgate (392 px).
// Phase 3: multiply the strip (256 ch x 98 float4), re-read L3-hot.
// Grid 256 blocks = 1/CU. No workspace, no atomics, no fences.
// ---------------------------------------------------------------------------
__global__ __launch_bounds__(256) void k_strip(const float4* __restrict__ x,
                                               const float* __restrict__ cw,
                                               const float* __restrict__ gamma,
                                               const float* __restrict__ beta,
                                               const float* __restrict__ rmean,
                                               const float* __restrict__ rvar,
                                               float4* __restrict__ out) {
    __shared__ float sw[99];
    __shared__ __align__(16) float smx[13 * SW];   // halo max rows
    __shared__ __align__(16) float sav[13 * SW];   // halo mean rows
    __shared__ __align__(16) float sgate[SROWS * SW];  // 392

    const int tid = threadIdx.x;
    const int b   = blockIdx.x >> 3;
    const int s   = blockIdx.x & 7;
    const int r0  = s * SROWS;                     // first output row
    const int h0  = (r0 - 3) > 0 ? (r0 - 3) : 0;   // first halo row
    const int h1  = (r0 + 9) < (SH - 1) ? (r0 + 9) : (SH - 1);
    const int nf4 = (h1 - h0 + 1) * 14;            // float4 in halo slab (<=182)

    const float inv = gamma[0] * rsqrtf(rvar[0] + 1e-5f);
    if (tid < 98) sw[tid] = cw[tid] * inv;
    if (tid == 0) sw[98] = beta[0] - rmean[0] * inv;

    // ---- Phase 1: reduce over channels (halo slab) ----
    if (tid < nf4) {
        const float4* base = x + (size_t)b * PERB4 + h0 * 14 + tid;
        const float NEG = -__builtin_inff();
        float4 m = make_float4(NEG, NEG, NEG, NEG);
        float4 sm = make_float4(0.f, 0.f, 0.f, 0.f);
        #pragma unroll 8
        for (int c = 0; c < NC; ++c) {
            const float4 v = base[(size_t)c * HW4];
            m = max4(m, v);
            sm = add4(sm, v);
        }
        const float r = 1.0f / 256.0f;
        sm.x *= r; sm.y *= r; sm.z *= r; sm.w *= r;
        ((float4*)smx)[tid] = m;
        ((float4*)sav)[tid] = sm;
    }
    __syncthreads();

    // ---- Phase 2: conv + BN + sigmoid (392 px, 2 per thread) ----
    if (tid < 196) {
        #pragma unroll
        for (int e = 0; e < 2; ++e) {
            const int px = 2 * tid + e;            // 0..391
            const int lr = px / SW;
            const int w  = px - lr * SW;
            const int h  = r0 + lr;
            float acc = sw[98];
            #pragma unroll
            for (int kh = 0; kh < 7; ++kh) {
                const int hh = h + kh - 3;
                if (hh < 0 || hh >= SH) continue;
                const int slot = hh - h0;          // 0..12
                #pragma unroll
                for (int kw = 0; kw < 7; ++kw) {
                    const int ww = w + kw - 3;
                    if (ww < 0 || ww >= SW) continue;
                    acc += smx[slot * SW + ww] * sw[kh * 7 + kw]
                         + sav[slot * SW + ww] * sw[49 + kh * 7 + kw];
                }
            }
            sgate[px] = 1.0f / (1.0f + expf(-acc));
        }
    }
    __syncthreads();

    // ---- Phase 3: multiply strip (256 ch x 98 float4, L3-hot re-read) ----
    const float4* sg4 = (const float4*)sgate;      // 98 float4
    const size_t sbase = (size_t)b * PERB4 + r0 * 14;
    #pragma unroll 4
    for (int it = 0; it < 98; ++it) {
        const unsigned idx = (unsigned)it * 256u + (unsigned)tid;  // 0..25087
        const unsigned c = idx / 98u;
        const unsigned q = idx - c * 98u;
        const size_t off = sbase + (size_t)c * HW4 + q;
        const float4 g  = sg4[q];
        const float4 xv = x[off];
        out[off] = make_float4(xv.x * g.x, xv.y * g.y, xv.z * g.z, xv.w * g.w);
    }
}

extern "C" void kernel_launch(void* const* d_in, const int* in_sizes, int n_in,
                              void* d_out, int out_size, void* d_ws, size_t ws_size,
                              hipStream_t stream) {
    const float4* x4   = (const float4*)d_in[0];
    const float* cw    = (const float*)d_in[1];
    const float* gamma = (const float*)d_in[2];
    const float* beta  = (const float*)d_in[3];
    const float* rmean = (const float*)d_in[4];
    const float* rvar  = (const float*)d_in[5];
    float4* out4 = (float4*)d_out;

    k_strip<<<NB * STRIPS, 256, 0, stream>>>(
        x4, cw, gamma, beta, rmean, rvar, out4);
}